// Round 10
// baseline (27578.714 us; speedup 1.0000x reference)
//
#include <hip/hip_runtime.h>

#define S_LEN 2048

typedef _Float16 f16;
typedef _Float16 f16x4 __attribute__((ext_vector_type(4)));
typedef _Float16 f16x8 __attribute__((ext_vector_type(8)));
typedef float f32x4 __attribute__((ext_vector_type(4)));

__device__ __forceinline__ float sigf(float x) {
  x = fminf(fmaxf(x, -30.f), 30.f);
  float e = __builtin_amdgcn_exp2f(-1.44269504089f * x);
  return __builtin_amdgcn_rcpf(1.f + e);
}
__device__ __forceinline__ float tanh_fast(float x) {
  x = fminf(fmaxf(x, -15.f), 15.f);
  float e = __builtin_amdgcn_exp2f(2.88539008178f * x);  // e^(2x)
  return 1.f - 2.f * __builtin_amdgcn_rcpf(e + 1.f);
}

// f16 copies of Wih/Whh ([1024][256] row-major), bias = bih + bhh.
__global__ void convert_k(const float* __restrict__ Wih, const float* __restrict__ Whh,
                          const float* __restrict__ bih, const float* __restrict__ bhh,
                          f16* __restrict__ Wih16, f16* __restrict__ Whh16,
                          float* __restrict__ bias) {
  int i = blockIdx.x * blockDim.x + threadIdx.x;  // 262144 threads
  Wih16[i] = (f16)Wih[i];
  Whh16[i] = (f16)Whh[i];
  if (i < 1024) bias[i] = bih[i] + bhh[i];
}

// pre[trel][n][b] = bias[n] + sum_e embed[text[b][t0+trel]][e] * Wih[n][e]
// One wg per timestep (512 thr / 8 waves). A = 64 gathered embed rows (f16,
// XOR-swizzled LDS); B = Wih16 streamed from L2 (shared across wgs).
__global__ __launch_bounds__(512, 1) void pre_k(
    const int* __restrict__ text, const float* __restrict__ embed,
    const f16* __restrict__ Wih16, const float* __restrict__ bias,
    f16* __restrict__ pre, int t0) {
  __shared__ __align__(16) f16 x_sw[64 * 256];
  const int tid = threadIdx.x, trel = blockIdx.x, t = t0 + trel;

  {  // gather + f16 + swizzled stage
    int b = tid >> 3, e0 = (tid & 7) * 32;
    int idx = text[(size_t)b * S_LEN + t];
    const float4* p = (const float4*)(embed + (size_t)idx * 256 + e0);
#pragma unroll
    for (int m = 0; m < 4; m++) {
      float4 v0 = p[2 * m], v1 = p[2 * m + 1];
      f16x8 hv = {(f16)v0.x, (f16)v0.y, (f16)v0.z, (f16)v0.w,
                  (f16)v1.x, (f16)v1.y, (f16)v1.z, (f16)v1.w};
      *(f16x8*)&x_sw[(b * 256 + e0 + m * 8) ^ ((b & 7) << 3)] = hv;
    }
  }
  __syncthreads();

  const int w = tid >> 6, l = tid & 63, kg = l >> 4, c16 = l & 15;
  const f16* wb = Wih16 + (size_t)(w * 128 + c16) * 256 + kg * 8;

  f32x4 acc[4][8];
#pragma unroll
  for (int mt = 0; mt < 4; mt++)
#pragma unroll
    for (int q = 0; q < 8; q++) acc[mt][q] = (f32x4){0.f, 0.f, 0.f, 0.f};

  f16x8 bcur[8], bnxt[8];
#pragma unroll
  for (int q = 0; q < 8; q++) bcur[q] = *(const f16x8*)(wb + q * 4096);

#pragma unroll
  for (int kc = 0; kc < 8; kc++) {
    if (kc < 7) {
#pragma unroll
      for (int q = 0; q < 8; q++)
        bnxt[q] = *(const f16x8*)(wb + q * 4096 + (kc + 1) * 32);
    }
#pragma unroll
    for (int mt = 0; mt < 4; mt++) {
      f16x8 a = *(const f16x8*)&x_sw[((mt * 16 + c16) * 256 + kc * 32 + kg * 8) ^ ((c16 & 7) << 3)];
#pragma unroll
      for (int q = 0; q < 8; q++)
        acc[mt][q] = __builtin_amdgcn_mfma_f32_16x16x32_f16(a, bcur[q], acc[mt][q], 0, 0, 0);
    }
#pragma unroll
    for (int q = 0; q < 8; q++) bcur[q] = bnxt[q];
  }

  // epilogue: +bias, cast f16, store [n][b] (f16x4 over 4 consecutive batches)
#pragma unroll
  for (int q = 0; q < 8; q++) {
    float badd = bias[w * 128 + q * 16 + c16];
#pragma unroll
    for (int mt = 0; mt < 4; mt++) {
      f16x4 hv = {(f16)(acc[mt][q][0] + badd), (f16)(acc[mt][q][1] + badd),
                  (f16)(acc[mt][q][2] + badd), (f16)(acc[mt][q][3] + badd)};
      *(f16x4*)&pre[((size_t)trel * 1024 + w * 128 + q * 16 + c16) * 64 + mt * 16 + kg * 4] = hv;
    }
  }
}

// Zero-communication recurrence: 4 wgs x 1024 thr (16 waves). Each wg owns 16
// batches and ALL 1024 gate-dims; Whh fully VGPR-resident (barr[4][8] = 128
// VGPR/lane, gate-per-tile). Per step: 512 MFMA (K=256 h-part), straight-line
// update (pre holds x-part+bias), h -> swizzled LDS double buffer, 1 barrier.
// State (c, h) spills to ws across chunk launches.
__global__ __launch_bounds__(1024, 1) void lstm_k(
    const f16* __restrict__ Whh16, const f16* __restrict__ pre,
    const float* __restrict__ mask, float* __restrict__ out,
    float* __restrict__ st_c, float* __restrict__ st_h, int t0, int tc) {
  __shared__ __align__(16) f16 h_sw[2 * 16 * 256];  // 16 KB parity buffers

  const int tid = threadIdx.x;
  const int b0 = blockIdx.x * 16;
  const int w = tid >> 6, l = tid & 63;
  const int kg = l >> 4, c16 = l & 15;
  const int jd = w * 16 + c16;  // this lane's dim (all 4 gates)
  const int tend = t0 + tc;

  // resident Whh: barr[gate][kc], row n = gate*256 + jd, k = kc*32 + kg*8
  f16x8 barr[4][8];
#pragma unroll
  for (int g = 0; g < 4; g++) {
    const f16* wp = Whh16 + (size_t)(g * 256 + jd) * 256 + kg * 8;
#pragma unroll
    for (int kc = 0; kc < 8; kc++) barr[g][kc] = *(const f16x8*)(wp + kc * 32);
  }

  float cc[4] = {0.f, 0.f, 0.f, 0.f};
  if (t0 > 0) {
#pragma unroll
    for (int i = 0; i < 4; i++) cc[i] = st_c[(size_t)(b0 + 4 * kg + i) * 256 + jd];
  }

  // init h parity buffer for t0 (zeros at t0==0, else persisted state)
  {
    f16x8 z = {(f16)0.f, (f16)0.f, (f16)0.f, (f16)0.f,
               (f16)0.f, (f16)0.f, (f16)0.f, (f16)0.f};
    ((f16x8*)h_sw)[tid] = z;  // 1024 x 8 = both buffers
    if (t0 > 0) {
      int r = tid >> 6, c4 = (tid & 63) * 4;
      float4 hv = *(const float4*)&st_h[(size_t)(b0 + r) * 256 + c4];
      f16* hb = &h_sw[(t0 & 1) * 4096];
#pragma unroll
      for (int j = 0; j < 4; j++)
        hb[(r * 256 + c4 + j) ^ ((r & 7) << 3)] = (f16)((j == 0) ? hv.x : (j == 1) ? hv.y : (j == 2) ? hv.z : hv.w);
    }
  }

  // prologue prefetch: pre + mask for t0
  f16x4 pxA[4], pxB[4];
  float mkA[4], mkB[4];
  auto ldpre = [&](int trel, f16x4 (&px)[4]) {
    const f16* pb = pre + (size_t)trel * 65536 + (size_t)jd * 64 + b0 + 4 * kg;
    px[0] = *(const f16x4*)(pb);
    px[1] = *(const f16x4*)(pb + 256 * 64);
    px[2] = *(const f16x4*)(pb + 512 * 64);
    px[3] = *(const f16x4*)(pb + 768 * 64);
  };
  auto ldmask = [&](int t, float (&mk)[4]) {
#pragma unroll
    for (int i = 0; i < 4; i++) mk[i] = mask[(size_t)(b0 + 4 * kg + i) * S_LEN + t];
  };
  ldpre(0, pxA);
  ldmask(t0, mkA);
  __syncthreads();

  auto step = [&](int t, f16x4 (&px)[4], float (&mk)[4], f16x4 (&pxn)[4], float (&mkn)[4]) {
    // h-part MFMA: gates(g) += h(t) @ Whh[g-rows]^T
    const f16* hs = &h_sw[(t & 1) * 4096];
    f32x4 a0 = {0.f, 0.f, 0.f, 0.f}, a1 = a0, a2 = a0, a3 = a0;
#pragma unroll
    for (int kc = 0; kc < 8; kc++) {
      f16x8 a = *(const f16x8*)&hs[(c16 * 256 + kc * 32 + kg * 8) ^ ((c16 & 7) << 3)];
      a0 = __builtin_amdgcn_mfma_f32_16x16x32_f16(a, barr[0][kc], a0, 0, 0, 0);
      a1 = __builtin_amdgcn_mfma_f32_16x16x32_f16(a, barr[1][kc], a1, 0, 0, 0);
      a2 = __builtin_amdgcn_mfma_f32_16x16x32_f16(a, barr[2][kc], a2, 0, 0, 0);
      a3 = __builtin_amdgcn_mfma_f32_16x16x32_f16(a, barr[3][kc], a3, 0, 0, 0);
    }

    // prefetch next step's pre/mask (hidden under this step's update + next MFMA)
    if (t + 1 < tend) {
      ldpre(t + 1 - t0, pxn);
      ldmask(t + 1, mkn);
    }

    // straight-line update: lane owns (batches 4kg..+3, dim jd), all 4 gates
    f16* hd = &h_sw[((t + 1) & 1) * 4096];
    const int last = (t == tend - 1);
#pragma unroll
    for (int i = 0; i < 4; i++) {
      float gi = a0[i] + (float)px[0][i];
      float gf = a1[i] + (float)px[1][i];
      float gG = a2[i] + (float)px[2][i];
      float go = a3[i] + (float)px[3][i];
      cc[i] = sigf(gf) * cc[i] + sigf(gi) * tanh_fast(gG);
      float h = sigf(go) * tanh_fast(cc[i]);
      int b = 4 * kg + i;
      out[((size_t)(b0 + b) * S_LEN + t) * 256 + jd] = h * mk[i];
      hd[(b * 256 + jd) ^ ((b & 7) << 3)] = (f16)h;
      if (last) {
        st_c[(size_t)(b0 + b) * 256 + jd] = cc[i];
        st_h[(size_t)(b0 + b) * 256 + jd] = h;
      }
    }
    __syncthreads();
  };

  int t = t0;
  while (t + 1 < tend) {
    step(t, pxA, mkA, pxB, mkB);
    step(t + 1, pxB, mkB, pxA, mkA);
    t += 2;
  }
  if (t < tend) step(t, pxA, mkA, pxB, mkB);
}

extern "C" void kernel_launch(void* const* d_in, const int* in_sizes, int n_in,
                              void* d_out, int out_size, void* d_ws, size_t ws_size,
                              hipStream_t stream) {
  const int* text = (const int*)d_in[0];
  const float* mask = (const float*)d_in[1];
  // d_in[2] = len_seq: sort + inverse-sort is a no-op -> unused
  const float* embed = (const float*)d_in[3];
  const float* Wih = (const float*)d_in[4];
  const float* Whh = (const float*)d_in[5];
  const float* bih = (const float*)d_in[6];
  const float* bhh = (const float*)d_in[7];
  float* out = (float*)d_out;

  char* ws = (char*)d_ws;
  f16* Wih16 = (f16*)ws;                  // 524,288 B
  f16* Whh16 = (f16*)(ws + 524288);       // 524,288 B
  float* bias = (float*)(ws + 1048576);   // 4,096 B
  float* st_c = (float*)(ws + 1052672);   // 65,536 B
  float* st_h = (float*)(ws + 1118208);   // 65,536 B
  const size_t PRE_OFF = 1183744;
  f16* pre = (f16*)(ws + PRE_OFF);        // T x 1024 x 64 f16 (131072 B per t)

  long T = 1;
  if (ws_size > PRE_OFF) T = (long)((ws_size - PRE_OFF) / 131072);
  if (T < 1) T = 1;
  if (T > S_LEN) T = S_LEN;

  convert_k<<<1024, 256, 0, stream>>>(Wih, Whh, bih, bhh, Wih16, Whh16, bias);
  for (int t0 = 0; t0 < S_LEN; t0 += (int)T) {
    int tc = (int)((S_LEN - t0 < T) ? (S_LEN - t0) : T);
    pre_k<<<tc, 512, 0, stream>>>(text, embed, Wih16, bias, pre, t0);
    lstm_k<<<4, 1024, 0, stream>>>(Whh16, pre, mask, out, st_c, st_h, t0, tc);
  }
}

// Round 11
// 4032.577 us; speedup vs baseline: 6.8390x; 6.8390x over previous
//
#include <hip/hip_runtime.h>

#define S_LEN 2048

typedef _Float16 f16;
typedef _Float16 f16x8 __attribute__((ext_vector_type(8)));
typedef float f32x4 __attribute__((ext_vector_type(4)));
typedef unsigned u32;
typedef unsigned long long u64;

__device__ __forceinline__ float sigf(float x) {
  x = fminf(fmaxf(x, -30.f), 30.f);
  float e = __builtin_amdgcn_exp2f(-1.44269504089f * x);
  return __builtin_amdgcn_rcpf(1.f + e);
}
__device__ __forceinline__ float tanh_fast(float x) {
  x = fminf(fmaxf(x, -15.f), 15.f);
  float e = __builtin_amdgcn_exp2f(2.88539008178f * x);  // e^(2x)
  return 1.f - 2.f * __builtin_amdgcn_rcpf(e + 1.f);
}
__device__ __forceinline__ void st_hx64(u64* p, u64 v) {
  __hip_atomic_store(p, v, __ATOMIC_RELAXED, __HIP_MEMORY_SCOPE_AGENT);
}
__device__ __forceinline__ u32 ld_hx(const u32* p) {
  return __hip_atomic_load(p, __ATOMIC_RELAXED, __HIP_MEMORY_SCOPE_AGENT);
}
__device__ __forceinline__ float swz8(float v) {
  int r = __builtin_amdgcn_ds_swizzle(__builtin_bit_cast(int, v), 0x201F);  // lane ^= 8
  return __builtin_bit_cast(float, r);
}

// Build W16[1024][512] = [Whh | Wih] f16, bias = bih + bhh, zero hx tag words.
__global__ void convert_k(const float* __restrict__ Wih, const float* __restrict__ Whh,
                          const float* __restrict__ bih, const float* __restrict__ bhh,
                          f16* __restrict__ W16, float* __restrict__ bias,
                          u32* __restrict__ hx) {
  int i = blockIdx.x * blockDim.x + threadIdx.x;  // 524288 threads
  int n = i >> 9, k = i & 511;
  W16[i] = (f16)((k < 256) ? Whh[n * 256 + k] : Wih[n * 256 + (k - 256)]);
  if (i < 1024) bias[i] = bih[i] + bhh[i];
  if (i < 32768) hx[i] = 0u;  // replay safety: stale tags would alias
}

// Persistent LSTM: 64 wgs = 8 groups (8 batch rows) x 8 N-slices (32 dims).
// = the proven r3 kernel (2980us) with three surgical changes:
//  1. coalesced u64 publish (batchA,batchB adjacent words, one relaxed store)
//  2. issue order: publish -> window issues -> poll-load issue -> xpart MFMA
//     -> check (first check waits only on poll loads; retries are pure 7-load
//     iterations, no masking, no sleep)
//  3. 4 ds_swizzles instead of 8 via source-side gsel selection (same values)
__global__ __launch_bounds__(256, 1) void lstm_k(
    const f16* __restrict__ W16, const float* __restrict__ bias,
    const int* __restrict__ text, const float* __restrict__ embed,
    const float* __restrict__ mask, float* __restrict__ out,
    u32* __restrict__ hx) {
  __shared__ __align__(16) f16 h_sw[2][16 * 256];  // 16 KB, parity buffers
  __shared__ __align__(16) f16 x_sw[4][16 * 256];  // 32 KB ring

  const int tid = threadIdx.x;
  const int g = blockIdx.x & 7;       // batch group (8 rows)
  const int slice = blockIdx.x >> 3;  // 32-dim N slice
  const int b0 = g * 8;
  const int j0 = slice * 32;

  // MFMA lane mapping: wave wv owns dims j0 + wv*8 .. +7
  const int wv = tid >> 6;
  const int l = tid & 63;
  const int kg = l >> 4;          // 0..3 (k-group; D rows 4kg..4kg+3)
  const int c16 = l & 15;         // B tile row / D col
  const int asw = (c16 & 7) << 3;
  const int gsel = c16 >> 3;      // 0: lane holds gates {i,g}; 1: {f,o}
  const int jloc = wv * 8 + (c16 & 7);
  const int jg = j0 + jloc;

  // prefetch / gather mapping
  const int r = tid >> 5;   // 0..7 batch row
  const int jl = tid & 31;  // dim-in-slice
  const int rsw = (r & 7) << 3;
  const int pd = jl * 8;

  // zero both h parity buffers (rows 8..15 = M padding, stay zero)
  {
    f16x8 z = {(f16)0.f, (f16)0.f, (f16)0.f, (f16)0.f,
               (f16)0.f, (f16)0.f, (f16)0.f, (f16)0.f};
    *(f16x8*)&h_sw[0][tid * 16] = z;
    *(f16x8*)&h_sw[0][tid * 16 + 8] = z;
    *(f16x8*)&h_sw[1][tid * 16] = z;
    *(f16x8*)&h_sw[1][tid * 16 + 8] = z;
  }

  const float bi = bias[0 * 256 + jg];
  const float bf = bias[1 * 256 + jg];
  const float bg = bias[2 * 256 + jg];
  const float bo = bias[3 * 256 + jg];

  // resident weights: tile0 rows = gate gsel, tile1 rows = gate 2+gsel, dim jg
  f16x8 barr0[16], barr1[16];
  {
    const f16* w0 = W16 + (size_t)(gsel * 256 + jg) * 512 + kg * 8;
    const f16* w1 = W16 + (size_t)((2 + gsel) * 256 + jg) * 512 + kg * 8;
#pragma unroll
    for (int kc = 0; kc < 16; kc++) {
      barr0[kc] = *(const f16x8*)(w0 + kc * 32);
      barr1[kc] = *(const f16x8*)(w1 + kc * 32);
    }
  }

  // update-lane batch assignment (lanes kg<2 do the update for 2 batches)
  const int upd = (kg < 2);
  const int bA = kg * 4 + gsel * 2;  // valid when upd
  const int bB = bA + 1;
  const int bAc = upd ? bA : 0;
  const int bBc = upd ? bB : 0;
  float ccA = 0.f, ccB = 0.f;

  // x ring prologue: slots 0..3 = x[0..3]
  const size_t trow = (size_t)(b0 + r) * S_LEN;
#pragma unroll 1
  for (int pf = 0; pf < 4; pf++) {
    int idx = text[trow + pf];
    const float4* ep = (const float4*)(embed + (size_t)idx * 256 + pd);
    float4 v0 = ep[0], v1 = ep[1];
    f16x8 hv = {(f16)v0.x, (f16)v0.y, (f16)v0.z, (f16)v0.w,
                (f16)v1.x, (f16)v1.y, (f16)v1.z, (f16)v1.w};
    *(f16x8*)&x_sw[pf][(r * 256 + pd) ^ rsw] = hv;
  }
  float4 rxa, rxb;
  int idx_r;
  {
    int idx4 = text[trow + 4];
    const float4* ep = (const float4*)(embed + (size_t)idx4 * 256 + pd);
    rxa = ep[0];
    rxb = ep[1];
    idx_r = text[trow + 5];
  }

  // partner poll offsets: word (g*8+ps)*256 + jl*8 + r  (new coalesced layout)
  int offs[7];
#pragma unroll
  for (int p = 0; p < 7; p++) {
    int ps = p + (p >= slice);
    offs[p] = (g * 8 + ps) * 256 + jl * 8 + r;
  }
  // publish u64 index: ((g*8+slice)*256 + jloc*8 + bA) / 2
  const int pub_idx = ((g * 8 + slice) * 256 + jloc * 8 + bAc) >> 1;

  float mA = mask[(size_t)(b0 + bAc) * S_LEN];
  float mB = mask[(size_t)(b0 + bBc) * S_LEN];

  __syncthreads();

  // x-part accumulators for t=0
  f32x4 xacc0 = {0.f, 0.f, 0.f, 0.f}, xacc1 = {0.f, 0.f, 0.f, 0.f};
#pragma unroll
  for (int kc = 0; kc < 8; kc++) {
    f16x8 a = *(const f16x8*)&x_sw[0][(c16 * 256 + kc * 32 + kg * 8) ^ asw];
    xacc0 = __builtin_amdgcn_mfma_f32_16x16x32_f16(a, barr0[8 + kc], xacc0, 0, 0, 0);
    xacc1 = __builtin_amdgcn_mfma_f32_16x16x32_f16(a, barr1[8 + kc], xacc1, 0, 0, 0);
  }

  for (int t = 0; t < S_LEN; t++) {
    // h-part MFMA (critical): acc = xacc + h_t @ Whh-slice^T
    const f16* hs = h_sw[t & 1];
    f32x4 acc0 = xacc0, acc1 = xacc1;
#pragma unroll
    for (int kc = 0; kc < 8; kc++) {
      f16x8 a = *(const f16x8*)&hs[(c16 * 256 + kc * 32 + kg * 8) ^ asw];
      acc0 = __builtin_amdgcn_mfma_f32_16x16x32_f16(a, barr0[kc], acc0, 0, 0, 0);
      acc1 = __builtin_amdgcn_mfma_f32_16x16x32_f16(a, barr1[kc], acc1, 0, 0, 0);
    }

    // in-wave gate exchange, 4 swizzles (source-side gsel selection)
    float s0a = gsel ? acc0[0] : acc0[2];
    float s0b = gsel ? acc0[1] : acc0[3];
    float s1a = gsel ? acc1[0] : acc1[2];
    float s1b = gsel ? acc1[1] : acc1[3];
    float r0a = swz8(s0a), r0b = swz8(s0b), r1a = swz8(s1a), r1b = swz8(s1b);

    float giA = (gsel ? r0a : acc0[0]) + bi;
    float gfA = (gsel ? acc0[2] : r0a) + bf;
    float ggA = (gsel ? r1a : acc1[0]) + bg;
    float goA = (gsel ? acc1[2] : r1a) + bo;
    float giB = (gsel ? r0b : acc0[1]) + bi;
    float gfB = (gsel ? acc0[3] : r0b) + bf;
    float ggB = (gsel ? r1b : acc1[1]) + bg;
    float goB = (gsel ? acc1[3] : r1b) + bo;

    ccA = sigf(gfA) * ccA + sigf(giA) * tanh_fast(ggA);
    float hA = sigf(goA) * tanh_fast(ccA);
    ccB = sigf(gfB) * ccB + sigf(giB) * tanh_fast(ggB);
    float hB = sigf(goB) * tanh_fast(ccB);

    const int par = (t + 1) & 1;
    u32* hb32 = hx + (size_t)par * 16384;
    f16* hd = h_sw[par];
    const u32 tagv = (u32)(t + 1);

    // 1) publish: one coalesced u64 (batchA word | batchB word), relaxed agent
    if (upd) {
      u32 wA = (tagv << 16) | (u32)__builtin_bit_cast(unsigned short, (f16)hA);
      u32 wB = (tagv << 16) | (u32)__builtin_bit_cast(unsigned short, (f16)hB);
      st_hx64((u64*)hb32 + pub_idx, ((u64)wB << 32) | wA);
      // own h into next parity LDS + masked output
      out[((size_t)(b0 + bA) * S_LEN + t) * 256 + jg] = hA * mA;
      out[((size_t)(b0 + bB) * S_LEN + t) * 256 + jg] = hB * mB;
      hd[(bA * 256 + jg) ^ ((bA & 7) << 3)] = (f16)hA;
      hd[(bB * 256 + jg) ^ ((bB & 7) << 3)] = (f16)hB;
    }

    if (t + 1 < S_LEN) {
      // 2) window issues (independent of partners' h)
      mA = mask[(size_t)(b0 + bAc) * S_LEN + (t + 1)];
      mB = mask[(size_t)(b0 + bBc) * S_LEN + (t + 1)];
      if (t + 4 < S_LEN) {  // write x[t+4] into slot t&3 (x[t] consumed)
        f16x8 hv = {(f16)rxa.x, (f16)rxa.y, (f16)rxa.z, (f16)rxa.w,
                    (f16)rxb.x, (f16)rxb.y, (f16)rxb.z, (f16)rxb.w};
        *(f16x8*)&x_sw[t & 3][(r * 256 + pd) ^ rsw] = hv;
      }
      if (t + 5 < S_LEN) {
        const float4* ep = (const float4*)(embed + (size_t)idx_r * 256 + pd);
        rxa = ep[0];
        rxb = ep[1];
      }
      if (t + 6 < S_LEN) idx_r = text[trow + t + 6];

      // 3) issue the 7 poll loads NOW (in flight during xpart below)
      u32 v0 = ld_hx(hb32 + offs[0]);
      u32 v1 = ld_hx(hb32 + offs[1]);
      u32 v2 = ld_hx(hb32 + offs[2]);
      u32 v3 = ld_hx(hb32 + offs[3]);
      u32 v4 = ld_hx(hb32 + offs[4]);
      u32 v5 = ld_hx(hb32 + offs[5]);
      u32 v6 = ld_hx(hb32 + offs[6]);

      // 4) x-part MFMA for t+1 (hides poll-load latency)
      {
        const f16* xs = x_sw[(t + 1) & 3];
        f32x4 nx0 = {0.f, 0.f, 0.f, 0.f}, nx1 = {0.f, 0.f, 0.f, 0.f};
#pragma unroll
        for (int kc = 0; kc < 8; kc++) {
          f16x8 a = *(const f16x8*)&xs[(c16 * 256 + kc * 32 + kg * 8) ^ asw];
          nx0 = __builtin_amdgcn_mfma_f32_16x16x32_f16(a, barr0[8 + kc], nx0, 0, 0, 0);
          nx1 = __builtin_amdgcn_mfma_f32_16x16x32_f16(a, barr1[8 + kc], nx1, 0, 0, 0);
        }
        xacc0 = nx0;
        xacc1 = nx1;
      }

      // 5) check; retries are pure 7-load iterations (no masking, no sleep)
      while (true) {
        u32 m01 = (v0 < v1) ? v0 : v1;
        u32 m23 = (v2 < v3) ? v2 : v3;
        u32 m45 = (v4 < v5) ? v4 : v5;
        u32 m0123 = (m01 < m23) ? m01 : m23;
        u32 m456 = (m45 < v6) ? m45 : v6;
        u32 mn = (m0123 < m456) ? m0123 : m456;
        if (__all((int)((mn >> 16) == tagv))) break;
        v0 = ld_hx(hb32 + offs[0]);
        v1 = ld_hx(hb32 + offs[1]);
        v2 = ld_hx(hb32 + offs[2]);
        v3 = ld_hx(hb32 + offs[3]);
        v4 = ld_hx(hb32 + offs[4]);
        v5 = ld_hx(hb32 + offs[5]);
        v6 = ld_hx(hb32 + offs[6]);
      }

      // 6) gather partner h -> h_sw parity buffer
      {
        int ps0 = 0 + (0 >= slice), ps1 = 1 + (1 >= slice), ps2 = 2 + (2 >= slice);
        int ps3 = 3 + (3 >= slice), ps4 = 4 + (4 >= slice), ps5 = 5 + (5 >= slice);
        int ps6 = 6 + (6 >= slice);
        hd[(r * 256 + ps0 * 32 + jl) ^ rsw] = __builtin_bit_cast(f16, (unsigned short)(v0 & 0xffffu));
        hd[(r * 256 + ps1 * 32 + jl) ^ rsw] = __builtin_bit_cast(f16, (unsigned short)(v1 & 0xffffu));
        hd[(r * 256 + ps2 * 32 + jl) ^ rsw] = __builtin_bit_cast(f16, (unsigned short)(v2 & 0xffffu));
        hd[(r * 256 + ps3 * 32 + jl) ^ rsw] = __builtin_bit_cast(f16, (unsigned short)(v3 & 0xffffu));
        hd[(r * 256 + ps4 * 32 + jl) ^ rsw] = __builtin_bit_cast(f16, (unsigned short)(v4 & 0xffffu));
        hd[(r * 256 + ps5 * 32 + jl) ^ rsw] = __builtin_bit_cast(f16, (unsigned short)(v5 & 0xffffu));
        hd[(r * 256 + ps6 * 32 + jl) ^ rsw] = __builtin_bit_cast(f16, (unsigned short)(v6 & 0xffffu));
      }
    }
    __syncthreads();
  }
}

extern "C" void kernel_launch(void* const* d_in, const int* in_sizes, int n_in,
                              void* d_out, int out_size, void* d_ws, size_t ws_size,
                              hipStream_t stream) {
  const int* text = (const int*)d_in[0];
  const float* mask = (const float*)d_in[1];
  // d_in[2] = len_seq: sort + inverse-sort is a no-op -> unused
  const float* embed = (const float*)d_in[3];
  const float* Wih = (const float*)d_in[4];
  const float* Whh = (const float*)d_in[5];
  const float* bih = (const float*)d_in[6];
  const float* bhh = (const float*)d_in[7];
  float* out = (float*)d_out;

  char* ws = (char*)d_ws;
  f16* W16 = (f16*)ws;                      // 1,048,576 B
  float* bias = (float*)(ws + 1048576);     // 4,096 B
  u32* hx = (u32*)(ws + 1052672);           // 131,072 B (2 x 64 x 256 u32)

  convert_k<<<2048, 256, 0, stream>>>(Wih, Whh, bih, bhh, W16, bias, hx);
  lstm_k<<<64, 256, 0, stream>>>(W16, bias, text, embed, mask, out, hx);
}